// Round 7
// baseline (6049.989 us; speedup 1.0000x reference)
//
#include <hip/hip_runtime.h>

// VectorQuantiser forward, MI355X fp32.
// N=65536 tokens (16x64x64, channel stride 4096), K=1024 codes, D=64.
//
// Round 7: R6 (correct, 6049us) proved the allocator is capped at 64 VGPRs
// (8 waves/EU occupancy target) and scratch-spills the 48-float accumulator
// set -> 19 GB scratch traffic, VALUBusy 3%. __launch_bounds__'s 2nd arg only
// raises the MINIMUM waves/EU; it never lowers the target. Fix: clamp the
// occupancy target with amdgpu_waves_per_eu(4,4) -> VGPR budget 512/4 = 128,
// matching the LDS ceiling (34.8KB x 4 blocks/CU) so no occupancy is lost.
// Code is otherwise IDENTICAL to the passing R6 kernel (frozen numerics:
// chain m consumes channels m,m+4,...,m+60 ascending, dot=(c0+c1)+(c2+c3),
// d=fadd(fsub(nzn2,en2),2*dot), packed-key argmax ties).

// ---- ws layout (bytes) ----
#define WS_ROW   0        // u64 wsrow[65536]
#define WS_COL2  524288   // u64 wscol2[1024][32]
#define WS_CNT   786432   // u32 counts[1024]
#define WS_LOSS  790528   // double loss_acc
#define WS_CLEAR 790536   // memset [0, WS_CLEAR)
#define WS_EN2   790592   // float en2[1024]
#define WS_NZN2  794688   // float nzn2[65536]
#define WS_COL   1056832  // u64 wscol[1024] (written fully by k_colreduce)
#define WS_BYTES 1065024

__device__ __forceinline__ unsigned int f32_ord(float x) {
    unsigned int b = __float_as_uint(x);
    return (b & 0x80000000u) ? ~b : (b | 0x80000000u);
}

// numpy pairwise sum of squares over 64 values. FROZEN (blessed numerics).
template <typename F>
__device__ __forceinline__ float np_pairwise64_sq(F get) {
    float r[8];
#pragma unroll
    for (int j = 0; j < 8; ++j) {
        float v = get(j);
        r[j] = __fmul_rn(v, v);
    }
#pragma unroll
    for (int i = 8; i < 64; i += 8) {
#pragma unroll
        for (int j = 0; j < 8; ++j) {
            float v = get(i + j);
            r[j] = __fadd_rn(r[j], __fmul_rn(v, v));
        }
    }
    return __fadd_rn(__fadd_rn(__fadd_rn(r[0], r[1]), __fadd_rn(r[2], r[3])),
                     __fadd_rn(__fadd_rn(r[4], r[5]), __fadd_rn(r[6], r[7])));
}

// ---- K_prep: blocks 0..255 nzn2[65536]; 256..259 en2[1024] ----
__global__ __launch_bounds__(256) void k_prep(const float* __restrict__ z,
                                              const float* __restrict__ emb,
                                              float* __restrict__ nzn2,
                                              float* __restrict__ en2) {
    const int bx = blockIdx.x;
    const int t  = threadIdx.x;
    if (bx < 256) {
        const int n  = bx * 256 + t;
        const int b  = n >> 12;
        const int hw = n & 4095;
        const float* zp = z + (size_t)b * 262144 + hw;
        nzn2[n] = -np_pairwise64_sq([&](int i) { return zp[(size_t)i * 4096]; });
    } else {
        const int k = (bx - 256) * 256 + t;
        const float* a = emb + (size_t)k * 64;
        en2[k] = np_pairwise64_sq([&](int i) { return a[i]; });
    }
}

// one chain: acc[i*4+c] += z[tok ty4+i][ch] * e[code tx4+c][ch], ch = 4j+M
template <int M>
__device__ __forceinline__ void chain_fma(const float* __restrict__ zs,
                                          const float* __restrict__ es,
                                          int ty4, int tx4, float* acc) {
#pragma unroll
    for (int j = 0; j < 16; ++j) {
        const int ch = 4 * j + M;
        const float4 zv = *reinterpret_cast<const float4*>(zs + ch * 68 + ty4);
        const float4 ev = *reinterpret_cast<const float4*>(es + ch * 68 + tx4);
        const float zz[4] = {zv.x, zv.y, zv.z, zv.w};
        const float ee[4] = {ev.x, ev.y, ev.z, ev.w};
#pragma unroll
        for (int i = 0; i < 4; ++i)
#pragma unroll
            for (int c = 0; c < 4; ++c)
                acc[i * 4 + c] = fmaf(zz[i], ee[c], acc[i * 4 + c]);
    }
}

// ---- K1: 64x64 tile GEMM + row/col argmax ----
// grid (1024 token-tiles, 16 code-tiles), block 256 (= 16 ty x 16 tx).
// waves_per_eu(4,4): occupancy target = 4 waves/EU (the LDS ceiling anyway)
// -> VGPR budget 128 -> the 48-float accumulator set stays in registers.
__global__ __launch_bounds__(256)
__attribute__((amdgpu_waves_per_eu(4, 4)))
void k_scores(
    const float* __restrict__ z, const float* __restrict__ emb,
    const float* __restrict__ en2, const float* __restrict__ nzn2,
    unsigned long long* __restrict__ wsrow,
    unsigned long long* __restrict__ wscol2) {
    const int t     = threadIdx.x;
    const int tile  = blockIdx.x;          // 64 tokens
    const int code0 = blockIdx.y * 64;     // 64 codes
    const int b     = tile >> 6;
    const int hw0   = (tile & 63) << 6;
    const int n0    = tile * 64;
    const int lane  = t & 63;
    const int wave  = t >> 6;
    const int tx    = t & 15, ty = t >> 4;
    const int tx4   = tx * 4, ty4 = ty * 4;

    __shared__ float smem[2 * 64 * 68];    // zs | es, 34816 B
    float* zs = smem;
    float* es = smem + 64 * 68;

    // stage z-tile: zs[ch][tok], coalesced global reads
    {
        const float* zbase = z + (size_t)b * 262144 + hw0;
        const int ch0 = (t >> 6) * 16;
#pragma unroll
        for (int i = 0; i < 16; ++i) {
            const int ch = ch0 + i;
            zs[ch * 68 + lane] = zbase[(size_t)ch * 4096 + lane];
        }
    }
    // stage e-tile transposed: es[ch][code] — all 64 codes
    {
        const int cl0 = t >> 4;            // 0..15
        const int ch4 = (t & 15) * 4;      // 0,4,...,60
#pragma unroll
        for (int q = 0; q < 4; ++q) {
            const int code_local = cl0 + 16 * q;
            const float4 e4 = *reinterpret_cast<const float4*>(
                emb + (size_t)(code0 + code_local) * 64 + ch4);
            es[(ch4 + 0) * 68 + code_local] = e4.x;
            es[(ch4 + 1) * 68 + code_local] = e4.y;
            es[(ch4 + 2) * 68 + code_local] = e4.z;
            es[(ch4 + 3) * 68 + code_local] = e4.w;
        }
    }
    __syncthreads();

    // chains (each bit-identical to blessed 4-chain dot: ascending j, stride 4)
    float A[16], B[16], C[16];
#pragma unroll
    for (int i = 0; i < 16; ++i) A[i] = 0.f;
    chain_fma<0>(zs, es, ty4, tx4, A);     // c0
#pragma unroll
    for (int i = 0; i < 16; ++i) B[i] = 0.f;
    chain_fma<1>(zs, es, ty4, tx4, B);     // c1
#pragma unroll
    for (int i = 0; i < 16; ++i) A[i] = A[i] + B[i];   // s01 = c0+c1
#pragma unroll
    for (int i = 0; i < 16; ++i) B[i] = 0.f;
    chain_fma<2>(zs, es, ty4, tx4, B);     // c2
#pragma unroll
    for (int i = 0; i < 16; ++i) C[i] = 0.f;
    chain_fma<3>(zs, es, ty4, tx4, C);     // c3

    // compose d into A: d = ((-zn2) - en2) + 2*((c0+c1)+(c2+c3))
    {
        float nz[4], ee[4];
#pragma unroll
        for (int i = 0; i < 4; ++i) nz[i] = nzn2[n0 + ty4 + i];
#pragma unroll
        for (int c = 0; c < 4; ++c) ee[c] = en2[code0 + tx4 + c];
#pragma unroll
        for (int i = 0; i < 4; ++i)
#pragma unroll
            for (int c = 0; c < 4; ++c) {
                float dot = A[i * 4 + c] + (B[i * 4 + c] + C[i * 4 + c]);
                A[i * 4 + c] =
                    __fadd_rn(__fsub_rn(nz[i], ee[c]), 2.0f * dot);
            }
    }

    // row argmax: per row i, local scan over 4 codes asc, then 16-lane tx merge
#pragma unroll
    for (int i = 0; i < 4; ++i) {
        float bv = A[i * 4];
        int   bc = code0 + tx4;
#pragma unroll
        for (int c = 1; c < 4; ++c) {
            float v = A[i * 4 + c];
            if (v > bv) { bv = v; bc = code0 + tx4 + c; }  // strict >
        }
        unsigned long long key =
            ((unsigned long long)f32_ord(bv) << 32) |
            (unsigned long long)(unsigned int)(~(unsigned int)bc);
#pragma unroll
        for (int m = 1; m < 16; m <<= 1) {
            unsigned long long o = __shfl_xor(key, m, 64);
            key = (o > key) ? o : key;     // ties -> larger ~k = smaller k
        }
        if (tx == 0) atomicMax(&wsrow[n0 + ty4 + i], key);
    }

    // col argmax: per col c, local scan over 4 tokens asc, reduce ty in-wave,
    // then cross-wave via LDS overlay, slice-decontended atomic.
    __syncthreads();                       // done reading zs/es
    unsigned long long* kcol = reinterpret_cast<unsigned long long*>(smem);
#pragma unroll
    for (int c = 0; c < 4; ++c) {
        float bv = A[c];
        int   bn = n0 + ty4;
#pragma unroll
        for (int i = 1; i < 4; ++i) {
            float v = A[i * 4 + c];
            if (v > bv) { bv = v; bn = n0 + ty4 + i; }   // strict >
        }
        unsigned long long key =
            ((unsigned long long)f32_ord(bv) << 32) |
            (unsigned long long)(unsigned int)(~(unsigned int)bn);
        unsigned long long o = __shfl_xor(key, 16, 64);
        key = (o > key) ? o : key;
        o = __shfl_xor(key, 32, 64);
        key = (o > key) ? o : key;         // ties -> smaller n
        if ((lane >> 4) == 0) kcol[wave * 64 + tx4 + c] = key;
    }
    __syncthreads();
    if (t < 64) {
        unsigned long long mk = kcol[t];
#pragma unroll
        for (int w = 1; w < 4; ++w) {
            unsigned long long o = kcol[w * 64 + t];
            mk = (o > mk) ? o : mk;
        }
        atomicMax(&wscol2[(size_t)(code0 + t) * 32 + (tile >> 5)], mk);
    }
}

// ---- K1b: fold 32 column slices -> wscol[1024] ----
__global__ __launch_bounds__(256) void k_colreduce(
    const unsigned long long* __restrict__ wscol2,
    unsigned long long* __restrict__ wscol) {
    const int code = blockIdx.x * 256 + threadIdx.x;
    const unsigned long long* s = wscol2 + (size_t)code * 32;
    unsigned long long m = s[0];
#pragma unroll
    for (int i = 1; i < 32; ++i) {
        unsigned long long o = s[i];
        m = (o > m) ? o : m;
    }
    wscol[code] = m;
}

// ---- K2: per-token outputs: z_q, indices, hist, loss ----
__global__ __launch_bounds__(256) void k_tokens(
    const float* __restrict__ z, const float* __restrict__ emb,
    const unsigned long long* __restrict__ wsrow,
    unsigned int* __restrict__ counts, double* __restrict__ loss_acc,
    float* __restrict__ out_zq, float* __restrict__ out_idx) {
    const int n  = blockIdx.x * 256 + threadIdx.x;
    const int b  = n >> 12;
    const int hw = n & 4095;

    unsigned long long key = wsrow[n];
    int idx = (int)(~(unsigned int)(key & 0xFFFFFFFFull));
    out_idx[n] = (float)idx;
    atomicAdd(&counts[idx], 1u);

    const float* zp = z + (size_t)b * 262144 + hw;
    float*       op = out_zq + (size_t)b * 262144 + hw;
    const float4* ep4 = reinterpret_cast<const float4*>(emb) + (size_t)idx * 16;

    double ls = 0.0;
#pragma unroll
    for (int j = 0; j < 16; ++j) {
        float4 eqv = ep4[j];
        float e4[4] = {eqv.x, eqv.y, eqv.z, eqv.w};
#pragma unroll
        for (int cc = 0; cc < 4; ++cc) {
            int c = 4 * j + cc;
            float zc   = zp[(size_t)c * 4096];
            float diff = __fsub_rn(e4[cc], zc);          // fl(z_q - zc)
            float sq   = __fmul_rn(diff, diff);
            ls += (double)sq;
            op[(size_t)c * 4096] = __fadd_rn(zc, diff);  // zc + fl(z_q - zc)
        }
    }

    __shared__ double sred[256];
    sred[threadIdx.x] = ls;
    __syncthreads();
    for (int st = 128; st; st >>= 1) {
        if (threadIdx.x < st) sred[threadIdx.x] += sred[threadIdx.x + st];
        __syncthreads();
    }
    if (threadIdx.x == 0) atomicAdd(loss_acc, sred[0]);
}

// ---- K3: fused scalars (block 256) + new embedding (blocks 0..255) ----
__global__ __launch_bounds__(256) void k_post(
    const float* __restrict__ z, const float* __restrict__ emb,
    const float* __restrict__ embed_prob,
    const unsigned long long* __restrict__ wscol,
    const unsigned int* __restrict__ counts,
    const double* __restrict__ loss_acc,
    float* __restrict__ out_loss, float* __restrict__ out_perp,
    float* __restrict__ out_newemb, float* __restrict__ out_prob) {
    const int t = threadIdx.x;
    if (blockIdx.x == 256) {
        double s = 0.0;
        for (int j = 0; j < 4; ++j) {
            int k = t + j * 256;
            float avg  = (float)counts[k] * (1.0f / 65536.0f);
            float pnew = __fadd_rn(__fmul_rn(embed_prob[k], 0.99f),
                                   __fmul_rn(0.01f, avg));
            out_prob[k] = pnew;
            s += (double)__fmul_rn(avg, logf(__fadd_rn(avg, 1e-10f)));
        }
        __shared__ double red[256];
        red[t] = s;
        __syncthreads();
        for (int st = 128; st; st >>= 1) {
            if (t < st) red[t] += red[t + st];
            __syncthreads();
        }
        if (t == 0) {
            out_perp[0] = expf(-(float)red[0]);
            double lm = loss_acc[0] / 4194304.0;
            float  m  = (float)lm;
            out_loss[0] = __fadd_rn(__fmul_rn(0.25f, m), m);  // BETA*m + m
        }
        return;
    }
    const int k = blockIdx.x * 4 + (t >> 6);
    const int c = t & 63;

    float avg  = (float)counts[k] * (1.0f / 65536.0f);
    float pnew = __fadd_rn(__fmul_rn(embed_prob[k], 0.99f),
                           __fmul_rn(0.01f, avg));
    float tt = __fdiv_rn(__fmul_rn(__fmul_rn(pnew, 1024.0f), 10.0f), 0.01f);
    float dk = expf(__fsub_rn(-tt, 1e-3f));
    float omd = __fsub_rn(1.0f, dk);

    unsigned long long ck = wscol[k];
    int cn  = (int)(~(unsigned int)(ck & 0xFFFFFFFFull));
    int cb  = cn >> 12;
    int chw = cn & 4095;

    float rf = z[(size_t)cb * 262144 + (size_t)c * 4096 + chw];
    float e  = emb[(size_t)k * 64 + c];
    out_newemb[(size_t)k * 64 + c] =
        __fadd_rn(__fmul_rn(e, omd), __fmul_rn(rf, dk));
}

extern "C" void kernel_launch(void* const* d_in, const int* in_sizes, int n_in,
                              void* d_out, int out_size, void* d_ws, size_t ws_size,
                              hipStream_t stream) {
    const float* z    = (const float*)d_in[0];   // 16*64*64*64
    const float* emb  = (const float*)d_in[1];   // 1024*64
    const float* prob = (const float*)d_in[2];   // 1024

    float* out        = (float*)d_out;
    float* out_zq     = out;                 // 4194304
    float* out_loss   = out + 4194304;       // 1
    float* out_perp   = out + 4194305;       // 1
    float* out_newemb = out + 4194306;       // 65536
    float* out_prob   = out + 4259842;       // 1024
    float* out_idx    = out + 4260866;       // 65536

    char* ws = (char*)d_ws;
    unsigned long long* wsrow  = (unsigned long long*)(ws + WS_ROW);
    unsigned long long* wscol2 = (unsigned long long*)(ws + WS_COL2);
    unsigned int*       cnts   = (unsigned int*)(ws + WS_CNT);
    double*             lacc   = (double*)(ws + WS_LOSS);
    float*              en2    = (float*)(ws + WS_EN2);
    float*              nzn2   = (float*)(ws + WS_NZN2);
    unsigned long long* wscol  = (unsigned long long*)(ws + WS_COL);

    hipMemsetAsync(d_ws, 0, WS_CLEAR, stream);

    hipLaunchKernelGGL(k_prep, dim3(260), dim3(256), 0, stream,
                       z, emb, nzn2, en2);
    hipLaunchKernelGGL(k_scores, dim3(1024, 16), dim3(256), 0, stream,
                       z, emb, en2, nzn2, wsrow, wscol2);
    hipLaunchKernelGGL(k_colreduce, dim3(4), dim3(256), 0, stream,
                       wscol2, wscol);
    hipLaunchKernelGGL(k_tokens, dim3(256), dim3(256), 0, stream,
                       z, emb, wsrow, cnts, lacc, out_zq, out_idx);
    hipLaunchKernelGGL(k_post, dim3(257), dim3(256), 0, stream,
                       z, emb, prob, wscol, cnts, lacc,
                       out_loss, out_perp, out_newemb, out_prob);
}